// Round 5
// baseline (501.693 us; speedup 1.0000x reference)
//
#include <hip/hip_runtime.h>
#include <math.h>

#define Bn 128
#define Nn 1000
#define Tn 50
#define En 32000
#define Rn 4
#define FSn 43
#define NSELn 500
#define NFtot (Nn * FSn)   // 43000

// ---------------------------------------------------------------------------
// Mid path, two-stage: conv1 (k=21) via register scatter, then conv2 (k=30).
// Covers t in [T0, T0+15). All loops fully unrolled -> static y indexing.
// NOTE: conv1 biases (bm0/bm1v/bm2) are inside the ReLU and must be supplied
// by BOTH halves; only the (linear) conv2 bias is split via acc init.
// ---------------------------------------------------------------------------
template<int T0>
__device__ __forceinline__ void mid_part(const float* __restrict__ lds, int lane,
    const float* __restrict__ w_m1, const float* __restrict__ w_m2,
    float bm0, float bm1v, float bm2, float* __restrict__ acc)
{
    float y0[15], y1[15], y2[15];
    #pragma unroll
    for (int t = 0; t < 15; ++t) { y0[t] = bm0; y1[t] = bm1v; y2[t] = bm2; }

    const int rb0 = (0 * 64 + lane) * 51;
    const int rb1 = (1 * 64 + lane) * 51;
    const int rb2 = (2 * 64 + lane) * 51;

    #pragma unroll
    for (int tau = T0; tau < T0 + 35; ++tau) {
        const int tlo = (tau - 20 > T0) ? (tau - 20) : T0;
        const int thi = (tau < T0 + 14) ? tau : (T0 + 14);
        const float o0 = lds[rb0 + tau];
        const float o1 = lds[rb1 + tau];
        const float o2 = lds[rb2 + tau];
        #pragma unroll
        for (int t = tlo; t <= thi; ++t) {
            const int d = tau - t;
            y0[t - T0] += o0 * w_m1[  0 + d] + o1 * w_m1[ 21 + d] + o2 * w_m1[ 42 + d];
            y1[t - T0] += o0 * w_m1[ 63 + d] + o1 * w_m1[ 84 + d] + o2 * w_m1[105 + d];
            y2[t - T0] += o0 * w_m1[126 + d] + o1 * w_m1[147 + d] + o2 * w_m1[168 + d];
        }
    }
    #pragma unroll
    for (int tt = 0; tt < 15; ++tt) {
        const float u0 = fmaxf(y0[tt], 0.f);
        const float u1 = fmaxf(y1[tt], 0.f);
        const float u2 = fmaxf(y2[tt], 0.f);
        #pragma unroll
        for (int o = 0; o < 20; ++o) {
            acc[o] += u0 * w_m2[(o * 3 + 0) * 30 + T0 + tt]
                    + u1 * w_m2[(o * 3 + 1) * 30 + T0 + tt]
                    + u2 * w_m2[(o * 3 + 2) * 30 + T0 + tt];
        }
    }
}

// ---------------------------------------------------------------------------
// Kernel 1: fused temporal features, 4-wave blocks, 64 nodes per block.
// w0/w1: short conv halves (sliding window) + long-max halves.
// w2/w3: mid conv halves (two-stage scatter).
// ---------------------------------------------------------------------------
__global__ __launch_bounds__(256, 4) void k_temporal(
    const float* __restrict__ obs,
    const float* __restrict__ w_s1, const float* __restrict__ b_s1,
    const float* __restrict__ w_s2, const float* __restrict__ b_s2,
    const float* __restrict__ w_m1, const float* __restrict__ b_m1,
    const float* __restrict__ w_m2, const float* __restrict__ b_m2,
    float* __restrict__ x)
{
    __shared__ float lds[3 * 64 * 51];

    const int b     = blockIdx.x;
    const int tile0 = blockIdx.y * 64;
    const int tid   = threadIdx.x;
    const int lane  = tid & 63;
    const int w     = __builtin_amdgcn_readfirstlane(tid >> 6);
    const int nrows = (Nn - tile0) < 64 ? (Nn - tile0) : 64;

    for (int c = 0; c < 3; ++c) {
        const float* srcp = obs + ((size_t)(b * 3 + c) * Nn + tile0) * Tn;
        for (int idx = tid; idx < nrows * Tn; idx += 256) {
            const int r = idx / Tn;
            const int t = idx - r * Tn;
            lds[(c * 64 + r) * 51 + t] = srcp[idx];
        }
    }
    __syncthreads();

    float acc[20];
    float mx0 = -1e30f, mx1 = -1e30f, mx2 = -1e30f;

    if (w < 2) {
        // ---------------- short path (sliding window) ----------------
        #pragma unroll
        for (int o = 0; o < 20; ++o) acc[o] = (w == 0) ? b_s2[o] : 0.f;

        const float s10 = b_s1[0], s11 = b_s1[1], s12 = b_s1[2];
        const int t0 = w * 24;
        const int base0 = (0 * 64 + lane) * 51 + t0;
        const int base1 = (1 * 64 + lane) * 51 + t0;
        const int base2 = (2 * 64 + lane) * 51 + t0;

        float a0 = lds[base0], p0 = lds[base0 + 1];
        float a1 = lds[base1], p1 = lds[base1 + 1];
        float a2 = lds[base2], p2 = lds[base2 + 1];

        #pragma unroll 3
        for (int t = 0; t < 24; ++t) {
            const float c0 = lds[base0 + t + 2];
            const float c1 = lds[base1 + t + 2];
            const float c2 = lds[base2 + t + 2];
            float v0 = s10 + a0 * w_s1[0]  + p0 * w_s1[1]  + c0 * w_s1[2]
                           + a1 * w_s1[3]  + p1 * w_s1[4]  + c1 * w_s1[5]
                           + a2 * w_s1[6]  + p2 * w_s1[7]  + c2 * w_s1[8];
            float v1 = s11 + a0 * w_s1[9]  + p0 * w_s1[10] + c0 * w_s1[11]
                           + a1 * w_s1[12] + p1 * w_s1[13] + c1 * w_s1[14]
                           + a2 * w_s1[15] + p2 * w_s1[16] + c2 * w_s1[17];
            float v2 = s12 + a0 * w_s1[18] + p0 * w_s1[19] + c0 * w_s1[20]
                           + a1 * w_s1[21] + p1 * w_s1[22] + c1 * w_s1[23]
                           + a2 * w_s1[24] + p2 * w_s1[25] + c2 * w_s1[26];
            v0 = fmaxf(v0, 0.f); v1 = fmaxf(v1, 0.f); v2 = fmaxf(v2, 0.f);
            const int tt = t0 + t;
            #pragma unroll
            for (int o = 0; o < 20; ++o) {
                acc[o] += v0 * w_s2[(o * 3 + 0) * 48 + tt]
                        + v1 * w_s2[(o * 3 + 1) * 48 + tt]
                        + v2 * w_s2[(o * 3 + 2) * 48 + tt];
            }
            a0 = p0; p0 = c0; a1 = p1; p1 = c1; a2 = p2; p2 = c2;
        }

        // ---------------- long path partial ----------------
        const int rb0 = (0 * 64 + lane) * 51;
        const int rb1 = (1 * 64 + lane) * 51;
        const int rb2 = (2 * 64 + lane) * 51;
        const int l0 = w * 25;
        #pragma unroll 5
        for (int t = l0; t < l0 + 25; ++t) {
            mx0 = fmaxf(mx0, lds[rb0 + t]);
            mx1 = fmaxf(mx1, lds[rb1 + t]);
            mx2 = fmaxf(mx2, lds[rb2 + t]);
        }
    } else {
        // ---------------- mid path ----------------
        #pragma unroll
        for (int o = 0; o < 20; ++o) acc[o] = (w == 2) ? b_m2[o] : 0.f;
        const float m10 = b_m1[0], m11 = b_m1[1], m12 = b_m1[2];
        // conv1 bias goes to BOTH halves (it's inside the ReLU)
        if (w == 2) mid_part<0 >(lds, lane, w_m1, w_m2, m10, m11, m12, acc);
        else        mid_part<15>(lds, lane, w_m1, w_m2, m10, m11, m12, acc);
    }

    // ---- exchange partials via the (now dead) obs tile ----
    __syncthreads();
    float* pshort = lds;               // [20][64]
    float* plong  = lds + 20 * 64;     // [3][64]
    float* pmid   = lds + 23 * 64;     // [20][64]

    if (w == 1) {
        #pragma unroll
        for (int o = 0; o < 20; ++o) pshort[o * 64 + lane] = acc[o];
        plong[0 * 64 + lane] = mx0;
        plong[1 * 64 + lane] = mx1;
        plong[2 * 64 + lane] = mx2;
    }
    if (w == 3) {
        #pragma unroll
        for (int o = 0; o < 20; ++o) pmid[o * 64 + lane] = acc[o];
    }
    __syncthreads();

    if (lane < nrows) {
        float* xp = x + ((size_t)b * Nn + tile0 + lane) * FSn;
        if (w == 0) {
            #pragma unroll
            for (int o = 0; o < 20; ++o)
                xp[o] = fmaxf(acc[o] + pshort[o * 64 + lane], 0.f);
            xp[40] = fmaxf(fmaxf(mx0, plong[0 * 64 + lane]), 0.f);
            xp[41] = fmaxf(fmaxf(mx1, plong[1 * 64 + lane]), 0.f);
            xp[42] = fmaxf(fmaxf(mx2, plong[2 * 64 + lane]), 0.f);
        } else if (w == 2) {
            #pragma unroll
            for (int o = 0; o < 20; ++o)
                xp[20 + o] = fmaxf(acc[o] + pmid[o * 64 + lane], 0.f);
        }
    }
}

// ---------------------------------------------------------------------------
// Transpose x[b][nf] (128 x 43000) -> xT[nf][b] (43000 x 128)
// ---------------------------------------------------------------------------
__global__ __launch_bounds__(256) void k_transpose(const float* __restrict__ x,
                                                   float* __restrict__ xT)
{
    __shared__ float tile[64][129];
    const int c0  = blockIdx.x * 64;
    const int tid = threadIdx.x;

    const int j  = tid & 63;
    const int bs = tid >> 6;
    for (int bb = bs; bb < Bn; bb += 4) {
        int c = c0 + j;
        if (c < NFtot) tile[j][bb] = x[(size_t)bb * NFtot + c];
    }
    __syncthreads();

    const int b  = tid & 127;
    for (int jj = (tid >> 7); jj < 64; jj += 2) {
        int c = c0 + jj;
        if (c < NFtot) xT[(size_t)c * Bn + b] = tile[jj][b];
    }
}

// ---------------------------------------------------------------------------
// CSR build
// ---------------------------------------------------------------------------
__global__ void k_zero(int* __restrict__ cnt, int* __restrict__ pos)
{
    int i = blockIdx.x * blockDim.x + threadIdx.x;
    if (i < 4096) { cnt[i] = 0; pos[i] = 0; }
}

__global__ void k_count(const int* __restrict__ ei, const int* __restrict__ et,
                        int* __restrict__ cnt)
{
    int e = blockIdx.x * blockDim.x + threadIdx.x;
    if (e < En) {
        int dst = ei[En + e];
        atomicAdd(&cnt[dst * Rn + et[e]], 1);
    }
}

__global__ __launch_bounds__(1024) void k_scan(const int* __restrict__ cnt,
                                               int* __restrict__ off)
{
    __shared__ int sums[1024];
    int tid = threadIdx.x;
    int base = tid * 4;
    int c[4];
    int ts = 0;
    #pragma unroll
    for (int k = 0; k < 4; ++k) {
        int i = base + k;
        c[k] = (i < Nn * Rn) ? cnt[i] : 0;
        ts += c[k];
    }
    sums[tid] = ts;
    __syncthreads();
    for (int d = 1; d < 1024; d <<= 1) {
        int t = 0;
        if (tid >= d) t = sums[tid - d];
        __syncthreads();
        sums[tid] += t;
        __syncthreads();
    }
    int excl = sums[tid] - ts;
    #pragma unroll
    for (int k = 0; k < 4; ++k) {
        int i = base + k;
        off[i] = excl;
        excl += c[k];
    }
}

__global__ void k_fill(const int* __restrict__ ei, const int* __restrict__ et,
                       const int* __restrict__ off, int* __restrict__ pos,
                       int* __restrict__ csr)
{
    int e = blockIdx.x * blockDim.x + threadIdx.x;
    if (e < En) {
        int src = ei[e];
        int dst = ei[En + e];
        int seg = dst * Rn + et[e];
        int p = atomicAdd(&pos[seg], 1);
        csr[off[seg] + p] = src;
    }
}

// ---------------------------------------------------------------------------
// Kernel 2a: per-(selected dst, relation) mean aggregation, float4 over b.
// grid = 500*4 blocks; 256 thr = 8 f-chunks x 32 b-quads.
// abar[i][r][f][b] = mean over edges of xT[src][f][b].
// ---------------------------------------------------------------------------
__global__ __launch_bounds__(256) void k_agg4(
    const float* __restrict__ xT,
    const int* __restrict__ csr, const int* __restrict__ off,
    const int* __restrict__ cnt, const int* __restrict__ sel,
    float* __restrict__ abar)
{
    __shared__ int srcs[128];

    const int blk = blockIdx.x;
    const int i   = blk >> 2;
    const int r   = blk & 3;
    const int dst = sel[i];
    const int tid = threadIdx.x;
    const int b4  = tid & 31;      // b quad index
    const int fc  = tid >> 5;      // 0..7

    const int seg = dst * Rn + r;
    const int c   = cnt[seg];
    const int o   = off[seg];
    const int cc  = (c < 128) ? c : 128;
    if (tid < cc) srcs[tid] = csr[o + tid];
    __syncthreads();

    const int nk = (fc < 3) ? 6 : 5;   // f = fc + 8k < 43

    float4 acc[6];
    #pragma unroll
    for (int k = 0; k < 6; ++k) acc[k] = make_float4(0.f, 0.f, 0.f, 0.f);

    const float4* xT4 = (const float4*)xT;
    for (int j = 0; j < cc; ++j) {
        const int src = srcs[j];
        const float4* base = xT4 + (size_t)src * (FSn * 32) + (size_t)fc * 32 + b4;
        #pragma unroll
        for (int k = 0; k < 6; ++k) {
            if (k < nk) {
                const float4 v = base[k * 8 * 32];
                acc[k].x += v.x; acc[k].y += v.y; acc[k].z += v.z; acc[k].w += v.w;
            }
        }
    }

    const float inv = (c > 0) ? 1.f / (float)c : 0.f;
    float4* ab4 = (float4*)abar + (size_t)(i * Rn + r) * (FSn * 32) + (size_t)fc * 32 + b4;
    #pragma unroll
    for (int k = 0; k < 6; ++k) {
        if (k < nk) {
            float4 v = acc[k];
            v.x *= inv; v.y *= inv; v.z *= inv; v.w *= inv;
            ab4[k * 8 * 32] = v;
        }
    }
}

// ---------------------------------------------------------------------------
// Kernel 2b: relational transform + root + leaky + final projection.
// grid = 500; 512 thr = 4 f-groups x 128 b. Reads abar + xT (root row).
// ---------------------------------------------------------------------------
__global__ __launch_bounds__(512) void k_trans(
    const float* __restrict__ xT, const float* __restrict__ abar,
    const float* __restrict__ w_rel, const float* __restrict__ w_root,
    const float* __restrict__ b_g,
    const float* __restrict__ w_fin, const float* __restrict__ b_fin,
    const float* __restrict__ la,
    const int* __restrict__ sel,
    float* __restrict__ logitT)
{
    __shared__ float red[FSn + 1][Bn];

    const int i   = blockIdx.x;
    const int dst = sel[i];
    const int tid = threadIdx.x;
    const int fs  = tid >> 7;
    const int b   = tid & 127;

    const int f0 = fs * 11;
    const int nf = (fs == 3) ? 10 : 11;

    float a[5][11];
    #pragma unroll
    for (int rr = 0; rr < 4; ++rr) {
        const float* ap = abar + ((size_t)(i * Rn + rr) * FSn + f0) * Bn + b;
        #pragma unroll
        for (int k = 0; k < 11; ++k)
            a[rr][k] = (k < nf) ? ap[(size_t)k * Bn] : 0.f;
    }
    {
        const float* xp = xT + ((size_t)dst * FSn + f0) * Bn + b;
        #pragma unroll
        for (int k = 0; k < 11; ++k)
            a[4][k] = (k < nf) ? xp[(size_t)k * Bn] : 0.f;
    }

    float accg[FSn];
    #pragma unroll
    for (int g = 0; g < FSn; ++g) accg[g] = 0.f;
    float psum = 0.f;

    #pragma unroll
    for (int k = 0; k < 11; ++k) {
        if (k < nf) {
            const int f = f0 + k;
            #pragma unroll
            for (int rr = 0; rr < 5; ++rr) {
                const float av = a[rr][k];
                const float* wrow = (rr < 4)
                    ? (w_rel + ((size_t)rr * FSn + f) * FSn)
                    : (w_root + (size_t)f * FSn);
                #pragma unroll
                for (int g = 0; g < FSn; ++g) accg[g] += av * wrow[g];
            }
            psum += a[4][k] * w_fin[1 + f];
        }
    }

    if (fs == 3) {
        #pragma unroll
        for (int g = 0; g < FSn; ++g) red[g][b] = accg[g];
        red[FSn][b] = psum;
    }
    __syncthreads();
    if (fs == 2) {
        #pragma unroll
        for (int g = 0; g < FSn; ++g) red[g][b] += accg[g];
        red[FSn][b] += psum;
    }
    __syncthreads();
    if (fs == 1) {
        #pragma unroll
        for (int g = 0; g < FSn; ++g) red[g][b] += accg[g];
        red[FSn][b] += psum;
    }
    __syncthreads();
    if (fs == 0) {
        float logit = b_fin[0] + w_fin[0] * la[(size_t)b * (NSELn + 1) + 1 + i]
                    + psum + red[FSn][b];
        #pragma unroll
        for (int g = 0; g < FSn; ++g) {
            float v = accg[g] + red[g][b] + b_g[g];
            v = (v > 0.f) ? v : 0.01f * v;
            logit += v * w_fin[44 + g];
        }
        logitT[(size_t)i * Bn + b] = logit;
    }
}

// ---------------------------------------------------------------------------
// Kernel 3: softmax over [0, logits(500)] per batch. Block per b.
// ---------------------------------------------------------------------------
__global__ __launch_bounds__(512) void k_softmax(const float* __restrict__ logitT,
                                                 float* __restrict__ out)
{
    __shared__ float red[512];
    const int b   = blockIdx.x;
    const int tid = threadIdx.x;

    const float l = (tid < NSELn) ? logitT[(size_t)tid * Bn + b] : -1e30f;
    red[tid] = l;
    __syncthreads();
    for (int s = 256; s > 0; s >>= 1) {
        if (tid < s) red[tid] = fmaxf(red[tid], red[tid + s]);
        __syncthreads();
    }
    const float m = fmaxf(red[0], 0.f);
    __syncthreads();

    const float e = (tid < NSELn) ? expf(l - m) : 0.f;
    red[tid] = e;
    __syncthreads();
    for (int s = 256; s > 0; s >>= 1) {
        if (tid < s) red[tid] += red[tid + s];
        __syncthreads();
    }
    const float e0  = expf(-m);
    const float inv = 1.f / (red[0] + e0);

    if (tid == 0) out[(size_t)b * (NSELn + 1)] = e0 * inv;
    if (tid < NSELn) out[(size_t)b * (NSELn + 1) + 1 + tid] = e * inv;
}

// ---------------------------------------------------------------------------
extern "C" void kernel_launch(void* const* d_in, const int* in_sizes, int n_in,
                              void* d_out, int out_size, void* d_ws, size_t ws_size,
                              hipStream_t stream)
{
    const float* obs    = (const float*)d_in[0];
    const float* la     = (const float*)d_in[1];
    const float* w_s1   = (const float*)d_in[2];
    const float* b_s1   = (const float*)d_in[3];
    const float* w_s2   = (const float*)d_in[4];
    const float* b_s2   = (const float*)d_in[5];
    const float* w_m1   = (const float*)d_in[6];
    const float* b_m1   = (const float*)d_in[7];
    const float* w_m2   = (const float*)d_in[8];
    const float* b_m2   = (const float*)d_in[9];
    const float* w_rel  = (const float*)d_in[10];
    const float* w_root = (const float*)d_in[11];
    const float* b_g    = (const float*)d_in[12];
    const float* w_fin  = (const float*)d_in[13];
    const float* b_fin  = (const float*)d_in[14];
    const int*   ei     = (const int*)d_in[15];
    const int*   et     = (const int*)d_in[16];
    const int*   sel    = (const int*)d_in[17];
    float*       out    = (float*)d_out;

    // workspace layout (x aliases the front of abar: x is dead before k_agg4
    // writes abar):
    //   abar : 500*4*43*128 = 11,008,000 floats (44 MB); x = first 5,504,000
    //   xT   : 5,504,000 floats (22 MB)
    //   cnt/off/pos : 4096 ints each;  csr : 32000 ints
    //   logitT : 500*128 floats
    float* abar   = (float*)d_ws;
    float* x      = abar;
    float* xT     = abar + 11008000;
    int*   cnt    = (int*)(xT + 5504000);
    int*   offb   = cnt + 4096;
    int*   pos    = offb + 4096;
    int*   csr    = pos + 4096;
    float* logitT = (float*)(csr + 32000);

    hipLaunchKernelGGL(k_zero,  dim3(16),  dim3(256), 0, stream, cnt, pos);
    hipLaunchKernelGGL(k_count, dim3((En + 255) / 256), dim3(256), 0, stream, ei, et, cnt);
    hipLaunchKernelGGL(k_scan,  dim3(1),   dim3(1024), 0, stream, cnt, offb);
    hipLaunchKernelGGL(k_fill,  dim3((En + 255) / 256), dim3(256), 0, stream, ei, et, offb, pos, csr);

    hipLaunchKernelGGL(k_temporal, dim3(Bn, (Nn + 63) / 64), dim3(256), 0, stream,
                       obs, w_s1, b_s1, w_s2, b_s2, w_m1, b_m1, w_m2, b_m2, x);

    hipLaunchKernelGGL(k_transpose, dim3((NFtot + 63) / 64), dim3(256), 0, stream, x, xT);

    hipLaunchKernelGGL(k_agg4, dim3(NSELn * Rn), dim3(256), 0, stream,
                       xT, csr, offb, cnt, sel, abar);

    hipLaunchKernelGGL(k_trans, dim3(NSELn), dim3(512), 0, stream,
                       xT, abar, w_rel, w_root, b_g, w_fin, b_fin, la, sel, logitT);

    hipLaunchKernelGGL(k_softmax, dim3(Bn), dim3(512), 0, stream, logitT, out);
}

// Round 6
// 326.149 us; speedup vs baseline: 1.5382x; 1.5382x over previous
//
#include <hip/hip_runtime.h>
#include <math.h>

#define Bn 128
#define Nn 1000
#define Tn 50
#define En 32000
#define Rn 4
#define FSn 43
#define NSELn 500
#define NFtot (Nn * FSn)   // 43000

// ---------------------------------------------------------------------------
// Mid conv chunk: conv1 (k=21, 3ch->3ch, bias+relu) for t in [T0, T0+8) via
// register scatter (each obs value read once), then conv2 (k=30 slice) into
// accM. T0 is wave-uniform runtime; all y indices compile-time (no scratch).
// jlo masks duplicated t's for the overlapping last chunk (T0=22, jlo=2).
// Live regs: y 24 + accM 20 -> fits comfortably in a 128-VGPR budget.
// ---------------------------------------------------------------------------
__device__ __forceinline__ void mid_chunk(const float* __restrict__ lds, int lane,
    int T0, int jlo,
    const float* __restrict__ w_m1, const float* __restrict__ w_m2,
    float bm0, float bm1v, float bm2, float* __restrict__ accM)
{
    float y0[8], y1[8], y2[8];
    #pragma unroll
    for (int j = 0; j < 8; ++j) { y0[j] = bm0; y1[j] = bm1v; y2[j] = bm2; }

    const int rb0 = (0 * 64 + lane) * 51 + T0;
    const int rb1 = (1 * 64 + lane) * 51 + T0;
    const int rb2 = (2 * 64 + lane) * 51 + T0;

    #pragma unroll
    for (int dt = 0; dt < 28; ++dt) {      // obs window [T0, T0+28)
        const float o0 = lds[rb0 + dt];
        const float o1 = lds[rb1 + dt];
        const float o2 = lds[rb2 + dt];
        #pragma unroll
        for (int j = 0; j < 8; ++j) {
            const int d = dt - j;          // compile-time per (dt,j)
            if (d >= 0 && d < 21) {
                y0[j] += o0 * w_m1[  0 + d] + o1 * w_m1[ 21 + d] + o2 * w_m1[ 42 + d];
                y1[j] += o0 * w_m1[ 63 + d] + o1 * w_m1[ 84 + d] + o2 * w_m1[105 + d];
                y2[j] += o0 * w_m1[126 + d] + o1 * w_m1[147 + d] + o2 * w_m1[168 + d];
            }
        }
    }
    #pragma unroll
    for (int j = 0; j < 8; ++j) {
        if (j >= jlo) {                    // uniform predicate (chunk overlap mask)
            const float u0 = fmaxf(y0[j], 0.f);
            const float u1 = fmaxf(y1[j], 0.f);
            const float u2 = fmaxf(y2[j], 0.f);
            const int tt = T0 + j;
            #pragma unroll
            for (int o = 0; o < 20; ++o) {
                accM[o] += u0 * w_m2[(o * 3 + 0) * 30 + tt]
                         + u1 * w_m2[(o * 3 + 1) * 30 + tt]
                         + u2 * w_m2[(o * 3 + 2) * 30 + tt];
            }
        }
    }
}

// ---------------------------------------------------------------------------
// Kernel 1: fused temporal features. 256 thr = 4 waves, 64 nodes per block.
// Every wave does: short conv chunk (12 t, sliding), mid conv chunk (8 t,
// scatter), long-max chunk. 4-way partials combined by wave 0 via LDS.
// amdgpu_waves_per_eu(4,4): LDS (39 KB) caps at 4 blocks/CU = 4 waves/EU, so
// pin the register budget at 128 VGPR to stop the allocator spilling for an
// occupancy it can never reach (R5 regression: 64 VGPR + 640 MB scratch).
// ---------------------------------------------------------------------------
__global__ __launch_bounds__(256)
__attribute__((amdgpu_waves_per_eu(4, 4)))
void k_temporal(
    const float* __restrict__ obs,
    const float* __restrict__ w_s1, const float* __restrict__ b_s1,
    const float* __restrict__ w_s2, const float* __restrict__ b_s2,
    const float* __restrict__ w_m1, const float* __restrict__ b_m1,
    const float* __restrict__ w_m2, const float* __restrict__ b_m2,
    float* __restrict__ x)
{
    __shared__ float lds[3 * 64 * 51];

    const int b     = blockIdx.x;
    const int tile0 = blockIdx.y * 64;
    const int tid   = threadIdx.x;
    const int lane  = tid & 63;
    const int w     = __builtin_amdgcn_readfirstlane(tid >> 6);
    const int nrows = (Nn - tile0) < 64 ? (Nn - tile0) : 64;

    for (int c = 0; c < 3; ++c) {
        const float* srcp = obs + ((size_t)(b * 3 + c) * Nn + tile0) * Tn;
        for (int idx = tid; idx < nrows * Tn; idx += 256) {
            const int r = idx / Tn;
            const int t = idx - r * Tn;
            lds[(c * 64 + r) * 51 + t] = srcp[idx];
        }
    }
    __syncthreads();

    // ---------------- short path chunk: t in [w*12, w*12+12) ----------------
    float accS[20];
    #pragma unroll
    for (int o = 0; o < 20; ++o) accS[o] = (w == 0) ? b_s2[o] : 0.f;
    {
        const float s10 = b_s1[0], s11 = b_s1[1], s12 = b_s1[2];
        const int t0 = w * 12;
        const int base0 = (0 * 64 + lane) * 51 + t0;
        const int base1 = (1 * 64 + lane) * 51 + t0;
        const int base2 = (2 * 64 + lane) * 51 + t0;

        float a0 = lds[base0], p0 = lds[base0 + 1];
        float a1 = lds[base1], p1 = lds[base1 + 1];
        float a2 = lds[base2], p2 = lds[base2 + 1];

        #pragma unroll 3
        for (int t = 0; t < 12; ++t) {
            const float c0 = lds[base0 + t + 2];
            const float c1 = lds[base1 + t + 2];
            const float c2 = lds[base2 + t + 2];
            float v0 = s10 + a0 * w_s1[0]  + p0 * w_s1[1]  + c0 * w_s1[2]
                           + a1 * w_s1[3]  + p1 * w_s1[4]  + c1 * w_s1[5]
                           + a2 * w_s1[6]  + p2 * w_s1[7]  + c2 * w_s1[8];
            float v1 = s11 + a0 * w_s1[9]  + p0 * w_s1[10] + c0 * w_s1[11]
                           + a1 * w_s1[12] + p1 * w_s1[13] + c1 * w_s1[14]
                           + a2 * w_s1[15] + p2 * w_s1[16] + c2 * w_s1[17];
            float v2 = s12 + a0 * w_s1[18] + p0 * w_s1[19] + c0 * w_s1[20]
                           + a1 * w_s1[21] + p1 * w_s1[22] + c1 * w_s1[23]
                           + a2 * w_s1[24] + p2 * w_s1[25] + c2 * w_s1[26];
            v0 = fmaxf(v0, 0.f); v1 = fmaxf(v1, 0.f); v2 = fmaxf(v2, 0.f);
            const int tt = t0 + t;
            #pragma unroll
            for (int o = 0; o < 20; ++o) {
                accS[o] += v0 * w_s2[(o * 3 + 0) * 48 + tt]
                         + v1 * w_s2[(o * 3 + 1) * 48 + tt]
                         + v2 * w_s2[(o * 3 + 2) * 48 + tt];
            }
            a0 = p0; p0 = c0; a1 = p1; p1 = c1; a2 = p2; p2 = c2;
        }
    }

    // ---------------- mid path chunk ----------------
    float accM[20];
    #pragma unroll
    for (int o = 0; o < 20; ++o) accM[o] = (w == 0) ? b_m2[o] : 0.f;
    {
        const int T0  = (w < 3) ? w * 8 : 22;   // chunks 0-7, 8-15, 16-23, 24-29
        const int jlo = (w < 3) ? 0 : 2;        // w3 skips duplicated t=22,23
        mid_chunk(lds, lane, T0, jlo, w_m1, w_m2, b_m1[0], b_m1[1], b_m1[2], accM);
    }

    // ---------------- long path chunk: t in [w*13, min(w*13+13,50)) ----------
    float mx0 = -1e30f, mx1 = -1e30f, mx2 = -1e30f;
    {
        const int rb0 = (0 * 64 + lane) * 51;
        const int rb1 = (1 * 64 + lane) * 51;
        const int rb2 = (2 * 64 + lane) * 51;
        const int l0 = w * 13;
        const int l1 = (l0 + 13 < Tn) ? l0 + 13 : Tn;
        #pragma unroll 1
        for (int t = l0; t < l1; ++t) {
            mx0 = fmaxf(mx0, lds[rb0 + t]);
            mx1 = fmaxf(mx1, lds[rb1 + t]);
            mx2 = fmaxf(mx2, lds[rb2 + t]);
        }
    }

    // ---- exchange 4-way partials via the (now dead) obs tile ----
    __syncthreads();
    float* pb = lds;                       // [3 waves][43][64]
    if (w > 0) {
        const int base = (w - 1) * (FSn * 64) + lane;
        #pragma unroll
        for (int o = 0; o < 20; ++o) pb[base + o * 64] = accS[o];
        #pragma unroll
        for (int o = 0; o < 20; ++o) pb[base + (20 + o) * 64] = accM[o];
        pb[base + 40 * 64] = mx0;
        pb[base + 41 * 64] = mx1;
        pb[base + 42 * 64] = mx2;
    }
    __syncthreads();

    if (w == 0 && lane < nrows) {
        float* xp = x + ((size_t)b * Nn + tile0 + lane) * FSn;
        const int s1 = FSn * 64, s2 = 2 * FSn * 64;
        #pragma unroll
        for (int o = 0; o < 20; ++o) {
            const int a = o * 64 + lane;
            xp[o] = fmaxf(accS[o] + pb[a] + pb[s1 + a] + pb[s2 + a], 0.f);
        }
        #pragma unroll
        for (int o = 0; o < 20; ++o) {
            const int a = (20 + o) * 64 + lane;
            xp[20 + o] = fmaxf(accM[o] + pb[a] + pb[s1 + a] + pb[s2 + a], 0.f);
        }
        {
            const int a0 = 40 * 64 + lane, a1 = 41 * 64 + lane, a2 = 42 * 64 + lane;
            xp[40] = fmaxf(fmaxf(fmaxf(mx0, pb[a0]), fmaxf(pb[s1 + a0], pb[s2 + a0])), 0.f);
            xp[41] = fmaxf(fmaxf(fmaxf(mx1, pb[a1]), fmaxf(pb[s1 + a1], pb[s2 + a1])), 0.f);
            xp[42] = fmaxf(fmaxf(fmaxf(mx2, pb[a2]), fmaxf(pb[s1 + a2], pb[s2 + a2])), 0.f);
        }
    }
}

// ---------------------------------------------------------------------------
// Transpose x[b][nf] (128 x 43000) -> xT[nf][b] (43000 x 128)
// ---------------------------------------------------------------------------
__global__ __launch_bounds__(256) void k_transpose(const float* __restrict__ x,
                                                   float* __restrict__ xT)
{
    __shared__ float tile[64][129];
    const int c0  = blockIdx.x * 64;
    const int tid = threadIdx.x;

    const int j  = tid & 63;
    const int bs = tid >> 6;
    for (int bb = bs; bb < Bn; bb += 4) {
        int c = c0 + j;
        if (c < NFtot) tile[j][bb] = x[(size_t)bb * NFtot + c];
    }
    __syncthreads();

    const int b  = tid & 127;
    for (int jj = (tid >> 7); jj < 64; jj += 2) {
        int c = c0 + jj;
        if (c < NFtot) xT[(size_t)c * Bn + b] = tile[jj][b];
    }
}

// ---------------------------------------------------------------------------
// CSR build
// ---------------------------------------------------------------------------
__global__ void k_zero(int* __restrict__ cnt, int* __restrict__ pos)
{
    int i = blockIdx.x * blockDim.x + threadIdx.x;
    if (i < 4096) { cnt[i] = 0; pos[i] = 0; }
}

__global__ void k_count(const int* __restrict__ ei, const int* __restrict__ et,
                        int* __restrict__ cnt)
{
    int e = blockIdx.x * blockDim.x + threadIdx.x;
    if (e < En) {
        int dst = ei[En + e];
        atomicAdd(&cnt[dst * Rn + et[e]], 1);
    }
}

__global__ __launch_bounds__(1024) void k_scan(const int* __restrict__ cnt,
                                               int* __restrict__ off)
{
    __shared__ int sums[1024];
    int tid = threadIdx.x;
    int base = tid * 4;
    int c[4];
    int ts = 0;
    #pragma unroll
    for (int k = 0; k < 4; ++k) {
        int i = base + k;
        c[k] = (i < Nn * Rn) ? cnt[i] : 0;
        ts += c[k];
    }
    sums[tid] = ts;
    __syncthreads();
    for (int d = 1; d < 1024; d <<= 1) {
        int t = 0;
        if (tid >= d) t = sums[tid - d];
        __syncthreads();
        sums[tid] += t;
        __syncthreads();
    }
    int excl = sums[tid] - ts;
    #pragma unroll
    for (int k = 0; k < 4; ++k) {
        int i = base + k;
        off[i] = excl;
        excl += c[k];
    }
}

__global__ void k_fill(const int* __restrict__ ei, const int* __restrict__ et,
                       const int* __restrict__ off, int* __restrict__ pos,
                       int* __restrict__ csr)
{
    int e = blockIdx.x * blockDim.x + threadIdx.x;
    if (e < En) {
        int src = ei[e];
        int dst = ei[En + e];
        int seg = dst * Rn + et[e];
        int p = atomicAdd(&pos[seg], 1);
        csr[off[seg] + p] = src;
    }
}

// ---------------------------------------------------------------------------
// Kernel 2a: per-(selected dst, relation) mean aggregation, float4 over b.
// grid = 500*4 blocks; 256 thr = 8 f-chunks x 32 b-quads.
// abar[i][r][f][b] = mean over edges of xT[src][f][b].
// ---------------------------------------------------------------------------
__global__ __launch_bounds__(256) void k_agg4(
    const float* __restrict__ xT,
    const int* __restrict__ csr, const int* __restrict__ off,
    const int* __restrict__ cnt, const int* __restrict__ sel,
    float* __restrict__ abar)
{
    __shared__ int srcs[128];

    const int blk = blockIdx.x;
    const int i   = blk >> 2;
    const int r   = blk & 3;
    const int dst = sel[i];
    const int tid = threadIdx.x;
    const int b4  = tid & 31;      // b quad index
    const int fc  = tid >> 5;      // 0..7

    const int seg = dst * Rn + r;
    const int c   = cnt[seg];
    const int o   = off[seg];
    const int cc  = (c < 128) ? c : 128;
    if (tid < cc) srcs[tid] = csr[o + tid];
    __syncthreads();

    const int nk = (fc < 3) ? 6 : 5;   // f = fc + 8k < 43

    float4 acc[6];
    #pragma unroll
    for (int k = 0; k < 6; ++k) acc[k] = make_float4(0.f, 0.f, 0.f, 0.f);

    const float4* xT4 = (const float4*)xT;
    for (int j = 0; j < cc; ++j) {
        const int src = srcs[j];
        const float4* base = xT4 + (size_t)src * (FSn * 32) + (size_t)fc * 32 + b4;
        #pragma unroll
        for (int k = 0; k < 6; ++k) {
            if (k < nk) {
                const float4 v = base[k * 8 * 32];
                acc[k].x += v.x; acc[k].y += v.y; acc[k].z += v.z; acc[k].w += v.w;
            }
        }
    }

    const float inv = (c > 0) ? 1.f / (float)c : 0.f;
    float4* ab4 = (float4*)abar + (size_t)(i * Rn + r) * (FSn * 32) + (size_t)fc * 32 + b4;
    #pragma unroll
    for (int k = 0; k < 6; ++k) {
        if (k < nk) {
            float4 v = acc[k];
            v.x *= inv; v.y *= inv; v.z *= inv; v.w *= inv;
            ab4[k * 8 * 32] = v;
        }
    }
}

// ---------------------------------------------------------------------------
// Kernel 2b: relational transform + root + leaky + final projection.
// grid = 500; 512 thr = 4 f-groups x 128 b. Reads abar + xT (root row).
// ---------------------------------------------------------------------------
__global__ __launch_bounds__(512) void k_trans(
    const float* __restrict__ xT, const float* __restrict__ abar,
    const float* __restrict__ w_rel, const float* __restrict__ w_root,
    const float* __restrict__ b_g,
    const float* __restrict__ w_fin, const float* __restrict__ b_fin,
    const float* __restrict__ la,
    const int* __restrict__ sel,
    float* __restrict__ logitT)
{
    __shared__ float red[FSn + 1][Bn];

    const int i   = blockIdx.x;
    const int dst = sel[i];
    const int tid = threadIdx.x;
    const int fs  = tid >> 7;
    const int b   = tid & 127;

    const int f0 = fs * 11;
    const int nf = (fs == 3) ? 10 : 11;

    float a[5][11];
    #pragma unroll
    for (int rr = 0; rr < 4; ++rr) {
        const float* ap = abar + ((size_t)(i * Rn + rr) * FSn + f0) * Bn + b;
        #pragma unroll
        for (int k = 0; k < 11; ++k)
            a[rr][k] = (k < nf) ? ap[(size_t)k * Bn] : 0.f;
    }
    {
        const float* xp = xT + ((size_t)dst * FSn + f0) * Bn + b;
        #pragma unroll
        for (int k = 0; k < 11; ++k)
            a[4][k] = (k < nf) ? xp[(size_t)k * Bn] : 0.f;
    }

    float accg[FSn];
    #pragma unroll
    for (int g = 0; g < FSn; ++g) accg[g] = 0.f;
    float psum = 0.f;

    #pragma unroll
    for (int k = 0; k < 11; ++k) {
        if (k < nf) {
            const int f = f0 + k;
            #pragma unroll
            for (int rr = 0; rr < 5; ++rr) {
                const float av = a[rr][k];
                const float* wrow = (rr < 4)
                    ? (w_rel + ((size_t)rr * FSn + f) * FSn)
                    : (w_root + (size_t)f * FSn);
                #pragma unroll
                for (int g = 0; g < FSn; ++g) accg[g] += av * wrow[g];
            }
            psum += a[4][k] * w_fin[1 + f];
        }
    }

    if (fs == 3) {
        #pragma unroll
        for (int g = 0; g < FSn; ++g) red[g][b] = accg[g];
        red[FSn][b] = psum;
    }
    __syncthreads();
    if (fs == 2) {
        #pragma unroll
        for (int g = 0; g < FSn; ++g) red[g][b] += accg[g];
        red[FSn][b] += psum;
    }
    __syncthreads();
    if (fs == 1) {
        #pragma unroll
        for (int g = 0; g < FSn; ++g) red[g][b] += accg[g];
        red[FSn][b] += psum;
    }
    __syncthreads();
    if (fs == 0) {
        float logit = b_fin[0] + w_fin[0] * la[(size_t)b * (NSELn + 1) + 1 + i]
                    + psum + red[FSn][b];
        #pragma unroll
        for (int g = 0; g < FSn; ++g) {
            float v = accg[g] + red[g][b] + b_g[g];
            v = (v > 0.f) ? v : 0.01f * v;
            logit += v * w_fin[44 + g];
        }
        logitT[(size_t)i * Bn + b] = logit;
    }
}

// ---------------------------------------------------------------------------
// Kernel 3: softmax over [0, logits(500)] per batch. Block per b.
// ---------------------------------------------------------------------------
__global__ __launch_bounds__(512) void k_softmax(const float* __restrict__ logitT,
                                                 float* __restrict__ out)
{
    __shared__ float red[512];
    const int b   = blockIdx.x;
    const int tid = threadIdx.x;

    const float l = (tid < NSELn) ? logitT[(size_t)tid * Bn + b] : -1e30f;
    red[tid] = l;
    __syncthreads();
    for (int s = 256; s > 0; s >>= 1) {
        if (tid < s) red[tid] = fmaxf(red[tid], red[tid + s]);
        __syncthreads();
    }
    const float m = fmaxf(red[0], 0.f);
    __syncthreads();

    const float e = (tid < NSELn) ? expf(l - m) : 0.f;
    red[tid] = e;
    __syncthreads();
    for (int s = 256; s > 0; s >>= 1) {
        if (tid < s) red[tid] += red[tid + s];
        __syncthreads();
    }
    const float e0  = expf(-m);
    const float inv = 1.f / (red[0] + e0);

    if (tid == 0) out[(size_t)b * (NSELn + 1)] = e0 * inv;
    if (tid < NSELn) out[(size_t)b * (NSELn + 1) + 1 + tid] = e * inv;
}

// ---------------------------------------------------------------------------
extern "C" void kernel_launch(void* const* d_in, const int* in_sizes, int n_in,
                              void* d_out, int out_size, void* d_ws, size_t ws_size,
                              hipStream_t stream)
{
    const float* obs    = (const float*)d_in[0];
    const float* la     = (const float*)d_in[1];
    const float* w_s1   = (const float*)d_in[2];
    const float* b_s1   = (const float*)d_in[3];
    const float* w_s2   = (const float*)d_in[4];
    const float* b_s2   = (const float*)d_in[5];
    const float* w_m1   = (const float*)d_in[6];
    const float* b_m1   = (const float*)d_in[7];
    const float* w_m2   = (const float*)d_in[8];
    const float* b_m2   = (const float*)d_in[9];
    const float* w_rel  = (const float*)d_in[10];
    const float* w_root = (const float*)d_in[11];
    const float* b_g    = (const float*)d_in[12];
    const float* w_fin  = (const float*)d_in[13];
    const float* b_fin  = (const float*)d_in[14];
    const int*   ei     = (const int*)d_in[15];
    const int*   et     = (const int*)d_in[16];
    const int*   sel    = (const int*)d_in[17];
    float*       out    = (float*)d_out;

    // workspace layout (x aliases the front of abar: x is dead before k_agg4
    // writes abar):
    //   abar : 500*4*43*128 = 11,008,000 floats (44 MB); x = first 5,504,000
    //   xT   : 5,504,000 floats (22 MB)
    //   cnt/off/pos : 4096 ints each;  csr : 32000 ints
    //   logitT : 500*128 floats
    float* abar   = (float*)d_ws;
    float* x      = abar;
    float* xT     = abar + 11008000;
    int*   cnt    = (int*)(xT + 5504000);
    int*   offb   = cnt + 4096;
    int*   pos    = offb + 4096;
    int*   csr    = pos + 4096;
    float* logitT = (float*)(csr + 32000);

    hipLaunchKernelGGL(k_zero,  dim3(16),  dim3(256), 0, stream, cnt, pos);
    hipLaunchKernelGGL(k_count, dim3((En + 255) / 256), dim3(256), 0, stream, ei, et, cnt);
    hipLaunchKernelGGL(k_scan,  dim3(1),   dim3(1024), 0, stream, cnt, offb);
    hipLaunchKernelGGL(k_fill,  dim3((En + 255) / 256), dim3(256), 0, stream, ei, et, offb, pos, csr);

    hipLaunchKernelGGL(k_temporal, dim3(Bn, (Nn + 63) / 64), dim3(256), 0, stream,
                       obs, w_s1, b_s1, w_s2, b_s2, w_m1, b_m1, w_m2, b_m2, x);

    hipLaunchKernelGGL(k_transpose, dim3((NFtot + 63) / 64), dim3(256), 0, stream, x, xT);

    hipLaunchKernelGGL(k_agg4, dim3(NSELn * Rn), dim3(256), 0, stream,
                       xT, csr, offb, cnt, sel, abar);

    hipLaunchKernelGGL(k_trans, dim3(NSELn), dim3(512), 0, stream,
                       xT, abar, w_rel, w_root, b_g, w_fin, b_fin, la, sel, logitT);

    hipLaunchKernelGGL(k_softmax, dim3(Bn), dim3(512), 0, stream, logitT, out);
}